// Round 1
// baseline (330.276 us; speedup 1.0000x reference)
//
#include <hip/hip_runtime.h>
#include <hip/hip_bf16.h>

#define H  1024
#define S  32768
#define H2 2048
#define H3 3072

typedef __attribute__((ext_vector_type(8))) short bf16x8;   // 8 bf16 = 4 VGPRs
typedef __attribute__((ext_vector_type(4))) float f32x4;    // MFMA C/D frag

// ---------- fp32 -> bf16 (RNE) helpers ----------
__device__ __forceinline__ unsigned short f2bf(float f) {
    unsigned u = __float_as_uint(f);
    u += 0x7fffu + ((u >> 16) & 1u);
    return (unsigned short)(u >> 16);
}

__device__ __forceinline__ unsigned cvt_pk(float lo, float hi) {
    __hip_bfloat162 h = __float22bfloat162_rn(make_float2(lo, hi));
    unsigned u;
    __builtin_memcpy(&u, &h, 4);
    return u;   // low 16 = lo, high 16 = hi
}

// ---------- async global->LDS 16B ----------
__device__ __forceinline__ void async_copy16(const void* g, void* l) {
    __builtin_amdgcn_global_load_lds(
        (const __attribute__((address_space(1))) unsigned int*)g,
        (__attribute__((address_space(3))) unsigned int*)l,
        16, 0, 0);
}

// ---------- prep: W2 = attn_w[:, 2048:3072] -> bf16 (row-major N x K) ----------
__global__ void prep_w2(const float* __restrict__ attn_w, unsigned short* __restrict__ w2b) {
    int idx4 = blockIdx.x * 256 + threadIdx.x;        // 0 .. 262143 (float4 chunks)
    int n = idx4 >> 8;                                 // 256 chunks per row
    int c = (idx4 & 255) * 4;
    float4 f = *(const float4*)(attn_w + (size_t)n * H3 + H2 + c);
    ushort4 u;
    u.x = f2bf(f.x); u.y = f2bf(f.y); u.z = f2bf(f.z); u.w = f2bf(f.w);
    *(ushort4*)(w2b + (size_t)n * H + c) = u;
}

// ---------- prep: d[i] = attn_b[i] + sum_k hidden[k] * attn_w[i][k], k<2048 ----------
__global__ void prep_d(const float* __restrict__ hidden, const float* __restrict__ attn_w,
                       const float* __restrict__ attn_b, float* __restrict__ dvec) {
    int wv = threadIdx.x >> 6, lane = threadIdx.x & 63;
    int row = blockIdx.x * 4 + wv;                     // grid 256 -> 1024 rows
    const float* wrow = attn_w + (size_t)row * H3;
    float s = 0.f;
    #pragma unroll
    for (int j = 0; j < 32; ++j) {
        int k = lane + j * 64;
        s += wrow[k] * hidden[k];
    }
    #pragma unroll
    for (int m = 1; m <= 32; m <<= 1) s += __shfl_xor(s, m);
    if (lane == 0) dvec[row] = s + attn_b[row];
}

// ---------- fused GEMM + tanh + v_w-dot + atomic row-accumulate ----------
// tile: BM=128, BN=128, BK=32; 256 threads (4 waves, 2x2 wave grid, 64x64/wave)
__global__ __launch_bounds__(256, 2) void attn_gemm(
        const float* __restrict__ enc, const unsigned short* __restrict__ w2b,
        const float* __restrict__ dvec, const float* __restrict__ vw,
        float* __restrict__ logits) {
    __shared__ unsigned short Atile[128 * 32];   // 8 KB bf16
    __shared__ unsigned short Btile[128 * 32];   // 8 KB bf16

    const int tid = threadIdx.x;
    const int rowBlock = blockIdx.x & 255;       // consecutive blocks share B chunk
    const int colBlock = blockIdx.x >> 8;        // 0..7

    const int lane = tid & 63;
    const int wv = tid >> 6;
    const int waveM = wv >> 1, waveN = wv & 1;
    const int quad = lane >> 4, l16 = lane & 15;

    f32x4 acc[4][4];
    #pragma unroll
    for (int mi = 0; mi < 4; ++mi)
        #pragma unroll
        for (int ni = 0; ni < 4; ++ni)
            acc[mi][ni] = (f32x4){0.f, 0.f, 0.f, 0.f};

    // staging index precompute
    const int arow = tid >> 3;            // 0..31 (+32 per pass)
    const int akc  = (tid & 7) * 4;       // float4 col within 32-wide K tile
    const size_t encRowBase = (size_t)(rowBlock * 128) * H;

    // LDS fragment base offsets (bytes constant across k-tiles)
    const unsigned short* Abase = Atile + (waveM * 64 + l16) * 32 + quad * 8;
    const unsigned short* Bbase = Btile + (waveN * 64 + l16) * 32 + quad * 8;

    for (int kt = 0; kt < 32; ++kt) {
        const int k0 = kt * 32;

        // --- stage B (pre-converted bf16) via async global->LDS, 2 x 16B per thread ---
        #pragma unroll
        for (int p = 0; p < 2; ++p) {
            int c = p * 256 + tid;                 // 16B chunk id, lane-contiguous per wave
            int n = c >> 2, kk = (c & 3) * 8;
            async_copy16(w2b + (size_t)(colBlock * 128 + n) * H + k0 + kk,
                         (char*)Btile + (size_t)c * 16);
        }

        // --- stage A: load fp32, convert to bf16, write LDS ---
        float4 av[4];
        #pragma unroll
        for (int p = 0; p < 4; ++p) {
            int row = arow + p * 32;
            av[p] = *(const float4*)(enc + encRowBase + (size_t)row * H + k0 + akc);
        }
        #pragma unroll
        for (int p = 0; p < 4; ++p) {
            int row = arow + p * 32;
            uint2 u;
            u.x = cvt_pk(av[p].x, av[p].y);
            u.y = cvt_pk(av[p].z, av[p].w);
            *(uint2*)(Atile + row * 32 + akc) = u;
        }

        __syncthreads();   // drains vmcnt (async B) + lgkm (A writes)

        // --- fragments + MFMA ---
        bf16x8 af[4], bfr[4];
        #pragma unroll
        for (int i = 0; i < 4; ++i) {
            af[i]  = *(const bf16x8*)(Abase + i * 16 * 32);
            bfr[i] = *(const bf16x8*)(Bbase + i * 16 * 32);
        }
        #pragma unroll
        for (int mi = 0; mi < 4; ++mi)
            #pragma unroll
            for (int ni = 0; ni < 4; ++ni)
                acc[mi][ni] = __builtin_amdgcn_mfma_f32_16x16x32_bf16(
                    af[mi], bfr[ni], acc[mi][ni], 0, 0, 0);

        __syncthreads();   // tile consumed; safe to overwrite next iter
    }

    // --- epilogue: logit[row] += sum_n tanh(acc + d[n]) * vw[n] ---
    float rowsum[4][4];
    #pragma unroll
    for (int mi = 0; mi < 4; ++mi)
        #pragma unroll
        for (int r = 0; r < 4; ++r) rowsum[mi][r] = 0.f;

    #pragma unroll
    for (int ni = 0; ni < 4; ++ni) {
        int colg = colBlock * 128 + waveN * 64 + ni * 16 + l16;
        float dv = dvec[colg];
        float vv = vw[colg];
        #pragma unroll
        for (int mi = 0; mi < 4; ++mi)
            #pragma unroll
            for (int r = 0; r < 4; ++r)
                rowsum[mi][r] += tanhf(acc[mi][ni][r] + dv) * vv;
    }

    // reduce across the 16 lanes holding the same row (l16 = 0..15)
    #pragma unroll
    for (int mi = 0; mi < 4; ++mi)
        #pragma unroll
        for (int r = 0; r < 4; ++r) {
            float s = rowsum[mi][r];
            s += __shfl_xor(s, 1);
            s += __shfl_xor(s, 2);
            s += __shfl_xor(s, 4);
            s += __shfl_xor(s, 8);
            rowsum[mi][r] = s;
        }

    if (l16 == 0) {
        int rbase = rowBlock * 128 + waveM * 64 + quad * 4;
        #pragma unroll
        for (int mi = 0; mi < 4; ++mi)
            #pragma unroll
            for (int r = 0; r < 4; ++r)
                atomicAdd(&logits[rbase + mi * 16 + r], rowsum[mi][r]);
    }
}

// ---------- softmax over 32768 logits, single workgroup, in-place ----------
__global__ __launch_bounds__(1024) void softmax_k(float* __restrict__ x) {
    __shared__ float red[16];
    const int tid = threadIdx.x;
    const int lane = tid & 63, wv = tid >> 6;

    float v[32];
    float m = -1e30f;
    #pragma unroll
    for (int i = 0; i < 32; ++i) {
        v[i] = x[tid + (i << 10)];
        m = fmaxf(m, v[i]);
    }
    #pragma unroll
    for (int o = 1; o < 64; o <<= 1) m = fmaxf(m, __shfl_xor(m, o));
    if (lane == 0) red[wv] = m;
    __syncthreads();
    #pragma unroll
    for (int i = 0; i < 16; ++i) m = fmaxf(m, red[i]);
    __syncthreads();

    float s = 0.f;
    #pragma unroll
    for (int i = 0; i < 32; ++i) {
        v[i] = expf(v[i] - m);
        s += v[i];
    }
    #pragma unroll
    for (int o = 1; o < 64; o <<= 1) s += __shfl_xor(s, o);
    if (lane == 0) red[wv] = s;
    __syncthreads();
    float tot = 0.f;
    #pragma unroll
    for (int i = 0; i < 16; ++i) tot += red[i];
    float inv = 1.0f / tot;

    #pragma unroll
    for (int i = 0; i < 32; ++i) x[tid + (i << 10)] = v[i] * inv;
}

extern "C" void kernel_launch(void* const* d_in, const int* in_sizes, int n_in,
                              void* d_out, int out_size, void* d_ws, size_t ws_size,
                              hipStream_t stream) {
    const float* hidden = (const float*)d_in[0];   // (1, 2048)
    const float* enc    = (const float*)d_in[1];   // (32768, 1024)
    const float* attn_w = (const float*)d_in[2];   // (1024, 3072)
    const float* attn_b = (const float*)d_in[3];   // (1024,)
    const float* v_w    = (const float*)d_in[4];   // (1, 1024)
    float* out = (float*)d_out;                    // (32768,) fp32

    unsigned short* w2b = (unsigned short*)d_ws;                    // 2 MB bf16 W2
    float* dvec = (float*)((char*)d_ws + (size_t)H * H * 2);        // 4 KB fused bias

    // logits accumulate into d_out via atomics -> must start at zero
    hipMemsetAsync(d_out, 0, (size_t)S * sizeof(float), stream);

    prep_w2<<<dim3(1024), dim3(256), 0, stream>>>(attn_w, w2b);
    prep_d<<<dim3(256), dim3(256), 0, stream>>>(hidden, attn_w, attn_b, dvec);
    attn_gemm<<<dim3(2048), dim3(256), 0, stream>>>(enc, w2b, dvec, v_w, out);
    softmax_k<<<dim3(1), dim3(1024), 0, stream>>>(out);
}

// Round 2
// 312.832 us; speedup vs baseline: 1.0558x; 1.0558x over previous
//
#include <hip/hip_runtime.h>
#include <hip/hip_bf16.h>

#define H  1024
#define S  32768
#define H2 2048
#define H3 3072

typedef __attribute__((ext_vector_type(8))) short bf16x8;   // 8 bf16 = 4 VGPRs
typedef __attribute__((ext_vector_type(4))) float f32x4;    // MFMA C/D frag

// ---------- fp32 -> bf16 (RNE) helpers ----------
__device__ __forceinline__ unsigned short f2bf(float f) {
    unsigned u = __float_as_uint(f);
    u += 0x7fffu + ((u >> 16) & 1u);
    return (unsigned short)(u >> 16);
}

__device__ __forceinline__ unsigned cvt_pk(float lo, float hi) {
    __hip_bfloat162 h = __float22bfloat162_rn(make_float2(lo, hi));
    unsigned u;
    __builtin_memcpy(&u, &h, 4);
    return u;   // low 16 = lo, high 16 = hi
}

// fast tanh via v_exp_f32: tanh(x) = 1 - 2/(e^(2x)+1); exact at +-inf saturation
__device__ __forceinline__ float tanh_fast(float x) {
    float e = __expf(2.0f * x);
    return 1.0f - 2.0f / (e + 1.0f);
}

// ---------- async global->LDS 16B ----------
__device__ __forceinline__ void async_copy16(const void* g, void* l) {
    __builtin_amdgcn_global_load_lds(
        (const __attribute__((address_space(1))) unsigned int*)g,
        (__attribute__((address_space(3))) unsigned int*)l,
        16, 0, 0);
}

// ---------- fused prep: enc->bf16 (fast path only), W2->bf16, dvec ----------
// fast path grid = 32768 + 1024 + 256; fallback grid = 1024 + 256 (do_enc=0)
__global__ void prep_all(const float* __restrict__ enc, const float* __restrict__ attn_w,
                         const float* __restrict__ attn_b, const float* __restrict__ hidden,
                         unsigned short* __restrict__ ebf, unsigned short* __restrict__ w2b,
                         float* __restrict__ dvec, int do_enc) {
    int b = blockIdx.x;
    if (do_enc) {
        if (b < 32768) {
            // enc fp32 -> bf16, 4 elems/thread, fully coalesced
            size_t idx4 = (size_t)b * 256 + threadIdx.x;       // float4 chunk id
            float4 f = ((const float4*)enc)[idx4];
            ushort4 u;
            u.x = f2bf(f.x); u.y = f2bf(f.y); u.z = f2bf(f.z); u.w = f2bf(f.w);
            ((ushort4*)ebf)[idx4] = u;
            return;
        }
        b -= 32768;
    }
    if (b < 1024) {
        // W2 = attn_w[:, 2048:3072] -> bf16 row-major (N=1024 x K=1024)
        int idx4 = b * 256 + threadIdx.x;                      // 0 .. 262143
        int n = idx4 >> 8;
        int c = (idx4 & 255) * 4;
        float4 f = *(const float4*)(attn_w + (size_t)n * H3 + H2 + c);
        ushort4 u;
        u.x = f2bf(f.x); u.y = f2bf(f.y); u.z = f2bf(f.z); u.w = f2bf(f.w);
        *(ushort4*)(w2b + (size_t)n * H + c) = u;
        return;
    }
    // dvec: d[i] = attn_b[i] + sum_{k<2048} hidden[k]*attn_w[i][k]; 256 blocks, 1 row/wave
    b -= 1024;
    int wv = threadIdx.x >> 6, lane = threadIdx.x & 63;
    int row = b * 4 + wv;
    const float* wrow = attn_w + (size_t)row * H3;
    float s = 0.f;
    #pragma unroll
    for (int j = 0; j < 32; ++j) {
        int k = lane + j * 64;
        s += wrow[k] * hidden[k];
    }
    #pragma unroll
    for (int m = 1; m <= 32; m <<= 1) s += __shfl_xor(s, m);
    if (lane == 0) dvec[row] = s + attn_b[row];
}

// ---------- shared epilogue: tanh + v_w-dot + shuffle-reduce + atomic ----------
__device__ __forceinline__ void epilogue(const f32x4 acc[4][4], const float* __restrict__ dvec,
                                         const float* __restrict__ vw, float* __restrict__ logits,
                                         int rowBlock, int colBlock, int waveM, int waveN,
                                         int quad, int l16) {
    float rowsum[4][4];
    #pragma unroll
    for (int mi = 0; mi < 4; ++mi)
        #pragma unroll
        for (int r = 0; r < 4; ++r) rowsum[mi][r] = 0.f;

    #pragma unroll
    for (int ni = 0; ni < 4; ++ni) {
        int colg = colBlock * 128 + waveN * 64 + ni * 16 + l16;
        float dv = dvec[colg];
        float vv = vw[colg];
        #pragma unroll
        for (int mi = 0; mi < 4; ++mi)
            #pragma unroll
            for (int r = 0; r < 4; ++r)
                rowsum[mi][r] += tanh_fast(acc[mi][ni][r] + dv) * vv;
    }

    // reduce across the 16 lanes (l16) holding the same output row
    #pragma unroll
    for (int mi = 0; mi < 4; ++mi)
        #pragma unroll
        for (int r = 0; r < 4; ++r) {
            float s = rowsum[mi][r];
            s += __shfl_xor(s, 1);
            s += __shfl_xor(s, 2);
            s += __shfl_xor(s, 4);
            s += __shfl_xor(s, 8);
            rowsum[mi][r] = s;
        }

    if (l16 == 0) {
        int rbase = rowBlock * 128 + waveM * 64 + quad * 4;
        #pragma unroll
        for (int mi = 0; mi < 4; ++mi)
            #pragma unroll
            for (int r = 0; r < 4; ++r)
                atomicAdd(&logits[rbase + mi * 16 + r], rowsum[mi][r]);
    }
}

// ---------- FAST gemm: both operands pre-converted bf16, pure global_load_lds staging ----------
// tile BM=128 BN=128 BK=32; 256 threads (2x2 waves, 64x64/wave)
__global__ __launch_bounds__(256, 2) void attn_gemm_fast(
        const unsigned short* __restrict__ ebf, const unsigned short* __restrict__ w2b,
        const float* __restrict__ dvec, const float* __restrict__ vw,
        float* __restrict__ logits) {
    __shared__ unsigned short Atile[128 * 32];   // 8 KB
    __shared__ unsigned short Btile[128 * 32];   // 8 KB

    const int tid = threadIdx.x;
    const int rowBlock = blockIdx.x & 255;       // first 256 blocks stream A once -> L3
    const int colBlock = blockIdx.x >> 8;        // 0..7

    const int lane = tid & 63;
    const int wv = tid >> 6;
    const int waveM = wv >> 1, waveN = wv & 1;
    const int quad = lane >> 4, l16 = lane & 15;

    f32x4 acc[4][4];
    #pragma unroll
    for (int mi = 0; mi < 4; ++mi)
        #pragma unroll
        for (int ni = 0; ni < 4; ++ni)
            acc[mi][ni] = (f32x4){0.f, 0.f, 0.f, 0.f};

    const unsigned short* Abase = Atile + (waveM * 64 + l16) * 32 + quad * 8;
    const unsigned short* Bbase = Btile + (waveN * 64 + l16) * 32 + quad * 8;

    const size_t aRow0 = (size_t)(rowBlock * 128) * H;
    const size_t bRow0 = (size_t)(colBlock * 128) * H;

    for (int kt = 0; kt < 32; ++kt) {
        const int k0 = kt * 32;

        // stage A and B: 2x16B each per thread, lane-contiguous LDS (global_load_lds rule)
        #pragma unroll
        for (int p = 0; p < 2; ++p) {
            int c = p * 256 + tid;                 // 16B chunk id 0..511
            int n = c >> 2, kk = (c & 3) * 8;
            async_copy16(ebf + aRow0 + (size_t)n * H + k0 + kk, (char*)Atile + (size_t)c * 16);
            async_copy16(w2b + bRow0 + (size_t)n * H + k0 + kk, (char*)Btile + (size_t)c * 16);
        }

        __syncthreads();   // compiler emits s_waitcnt vmcnt(0) before s_barrier

        bf16x8 af[4], bfr[4];
        #pragma unroll
        for (int i = 0; i < 4; ++i) {
            af[i]  = *(const bf16x8*)(Abase + i * 16 * 32);
            bfr[i] = *(const bf16x8*)(Bbase + i * 16 * 32);
        }
        #pragma unroll
        for (int mi = 0; mi < 4; ++mi)
            #pragma unroll
            for (int ni = 0; ni < 4; ++ni)
                acc[mi][ni] = __builtin_amdgcn_mfma_f32_16x16x32_bf16(
                    af[mi], bfr[ni], acc[mi][ni], 0, 0, 0);

        __syncthreads();
    }

    epilogue(acc, dvec, vw, logits, rowBlock, colBlock, waveM, waveN, quad, l16);
}

// ---------- FALLBACK gemm (small ws): inline fp32->bf16 A staging (round-1 proven) ----------
__global__ __launch_bounds__(256, 2) void attn_gemm_fb(
        const float* __restrict__ enc, const unsigned short* __restrict__ w2b,
        const float* __restrict__ dvec, const float* __restrict__ vw,
        float* __restrict__ logits) {
    __shared__ unsigned short Atile[128 * 32];
    __shared__ unsigned short Btile[128 * 32];

    const int tid = threadIdx.x;
    const int rowBlock = blockIdx.x & 255;
    const int colBlock = blockIdx.x >> 8;

    const int lane = tid & 63;
    const int wv = tid >> 6;
    const int waveM = wv >> 1, waveN = wv & 1;
    const int quad = lane >> 4, l16 = lane & 15;

    f32x4 acc[4][4];
    #pragma unroll
    for (int mi = 0; mi < 4; ++mi)
        #pragma unroll
        for (int ni = 0; ni < 4; ++ni)
            acc[mi][ni] = (f32x4){0.f, 0.f, 0.f, 0.f};

    const int arow = tid >> 3;
    const int akc  = (tid & 7) * 4;
    const size_t encRowBase = (size_t)(rowBlock * 128) * H;

    const unsigned short* Abase = Atile + (waveM * 64 + l16) * 32 + quad * 8;
    const unsigned short* Bbase = Btile + (waveN * 64 + l16) * 32 + quad * 8;

    for (int kt = 0; kt < 32; ++kt) {
        const int k0 = kt * 32;
        #pragma unroll
        for (int p = 0; p < 2; ++p) {
            int c = p * 256 + tid;
            int n = c >> 2, kk = (c & 3) * 8;
            async_copy16(w2b + (size_t)(colBlock * 128 + n) * H + k0 + kk,
                         (char*)Btile + (size_t)c * 16);
        }
        float4 av[4];
        #pragma unroll
        for (int p = 0; p < 4; ++p)
            av[p] = *(const float4*)(enc + encRowBase + (size_t)(arow + p * 32) * H + k0 + akc);
        #pragma unroll
        for (int p = 0; p < 4; ++p) {
            uint2 u;
            u.x = cvt_pk(av[p].x, av[p].y);
            u.y = cvt_pk(av[p].z, av[p].w);
            *(uint2*)(Atile + (arow + p * 32) * 32 + akc) = u;
        }

        __syncthreads();

        bf16x8 af[4], bfr[4];
        #pragma unroll
        for (int i = 0; i < 4; ++i) {
            af[i]  = *(const bf16x8*)(Abase + i * 16 * 32);
            bfr[i] = *(const bf16x8*)(Bbase + i * 16 * 32);
        }
        #pragma unroll
        for (int mi = 0; mi < 4; ++mi)
            #pragma unroll
            for (int ni = 0; ni < 4; ++ni)
                acc[mi][ni] = __builtin_amdgcn_mfma_f32_16x16x32_bf16(
                    af[mi], bfr[ni], acc[mi][ni], 0, 0, 0);

        __syncthreads();
    }

    epilogue(acc, dvec, vw, logits, rowBlock, colBlock, waveM, waveN, quad, l16);
}

// ---------- softmax over 32768 logits, single workgroup, in-place ----------
__global__ __launch_bounds__(1024) void softmax_k(float* __restrict__ x) {
    __shared__ float red[16];
    const int tid = threadIdx.x;
    const int lane = tid & 63, wv = tid >> 6;

    float v[32];
    float m = -1e30f;
    #pragma unroll
    for (int i = 0; i < 32; ++i) {
        v[i] = x[tid + (i << 10)];
        m = fmaxf(m, v[i]);
    }
    #pragma unroll
    for (int o = 1; o < 64; o <<= 1) m = fmaxf(m, __shfl_xor(m, o));
    if (lane == 0) red[wv] = m;
    __syncthreads();
    #pragma unroll
    for (int i = 0; i < 16; ++i) m = fmaxf(m, red[i]);
    __syncthreads();

    float s = 0.f;
    #pragma unroll
    for (int i = 0; i < 32; ++i) {
        v[i] = expf(v[i] - m);
        s += v[i];
    }
    #pragma unroll
    for (int o = 1; o < 64; o <<= 1) s += __shfl_xor(s, o);
    if (lane == 0) red[wv] = s;
    __syncthreads();
    float tot = 0.f;
    #pragma unroll
    for (int i = 0; i < 16; ++i) tot += red[i];
    float inv = 1.0f / tot;

    #pragma unroll
    for (int i = 0; i < 32; ++i) x[tid + (i << 10)] = v[i] * inv;
}

extern "C" void kernel_launch(void* const* d_in, const int* in_sizes, int n_in,
                              void* d_out, int out_size, void* d_ws, size_t ws_size,
                              hipStream_t stream) {
    const float* hidden = (const float*)d_in[0];   // (1, 2048)
    const float* enc    = (const float*)d_in[1];   // (32768, 1024)
    const float* attn_w = (const float*)d_in[2];   // (1024, 3072)
    const float* attn_b = (const float*)d_in[3];   // (1024,)
    const float* v_w    = (const float*)d_in[4];   // (1, 1024)
    float* out = (float*)d_out;                    // (32768,) fp32

    // fast path needs: enc bf16 (64 MB) + W2 bf16 (2 MB) + dvec (4 KB)
    const size_t EBF_BYTES = (size_t)S * H * 2;
    const size_t W2_BYTES  = (size_t)H * H * 2;
    const bool fast = ws_size >= EBF_BYTES + W2_BYTES + 4096;

    // logits accumulate into d_out via atomics -> zero first
    hipMemsetAsync(d_out, 0, (size_t)S * sizeof(float), stream);

    if (fast) {
        unsigned short* ebf = (unsigned short*)d_ws;
        unsigned short* w2b = (unsigned short*)((char*)d_ws + EBF_BYTES);
        float* dvec = (float*)((char*)d_ws + EBF_BYTES + W2_BYTES);
        prep_all<<<dim3(32768 + 1024 + 256), dim3(256), 0, stream>>>(
            enc, attn_w, attn_b, hidden, ebf, w2b, dvec, 1);
        attn_gemm_fast<<<dim3(2048), dim3(256), 0, stream>>>(ebf, w2b, dvec, v_w, out);
    } else {
        unsigned short* w2b = (unsigned short*)d_ws;
        float* dvec = (float*)((char*)d_ws + W2_BYTES);
        prep_all<<<dim3(1024 + 256), dim3(256), 0, stream>>>(
            enc, attn_w, attn_b, hidden, nullptr, w2b, dvec, 0);
        attn_gemm_fb<<<dim3(2048), dim3(256), 0, stream>>>(enc, w2b, dvec, v_w, out);
    }
    softmax_k<<<dim3(1), dim3(1024), 0, stream>>>(out);
}

// Round 4
// 307.376 us; speedup vs baseline: 1.0745x; 1.0178x over previous
//
#include <hip/hip_runtime.h>
#include <hip/hip_bf16.h>

#define H  1024
#define S  32768
#define H2 2048
#define H3 3072

typedef __attribute__((ext_vector_type(8))) short bf16x8;   // 8 bf16 = 4 VGPRs
typedef __attribute__((ext_vector_type(4))) float f32x4;    // MFMA C/D frag

// ---------- fp32 -> bf16 (RNE) helpers ----------
__device__ __forceinline__ unsigned short f2bf(float f) {
    unsigned u = __float_as_uint(f);
    u += 0x7fffu + ((u >> 16) & 1u);
    return (unsigned short)(u >> 16);
}

__device__ __forceinline__ unsigned cvt_pk(float lo, float hi) {
    __hip_bfloat162 h = __float22bfloat162_rn(make_float2(lo, hi));
    unsigned u;
    __builtin_memcpy(&u, &h, 4);
    return u;
}

// fast tanh via v_exp_f32: tanh(x) = 1 - 2/(e^(2x)+1)
__device__ __forceinline__ float tanh_fast(float x) {
    float e = __expf(2.0f * x);
    return 1.0f - 2.0f / (e + 1.0f);
}

// ---------- async global->LDS 16B ----------
__device__ __forceinline__ void async_copy16(const void* g, void* l) {
    __builtin_amdgcn_global_load_lds(
        (const __attribute__((address_space(1))) unsigned int*)g,
        (__attribute__((address_space(3))) unsigned int*)l,
        16, 0, 0);
}

// ---------- fused prep: zero logits, enc->bf16 (fast path), W2->bf16, dvec ----------
// grid = 32 [+32768 if do_enc] + 1024 + 256
__global__ void prep_all(const float* __restrict__ enc, const float* __restrict__ attn_w,
                         const float* __restrict__ attn_b, const float* __restrict__ hidden,
                         unsigned short* __restrict__ ebf, unsigned short* __restrict__ w2b,
                         float* __restrict__ dvec, float* __restrict__ logits, int do_enc) {
    int b = blockIdx.x;
    if (b < 32) {
        // zero the logits (gemm accumulates via atomicAdd)
        ((float4*)logits)[b * 256 + threadIdx.x] = (float4){0.f, 0.f, 0.f, 0.f};
        return;
    }
    b -= 32;
    if (do_enc) {
        if (b < 32768) {
            size_t idx4 = (size_t)b * 256 + threadIdx.x;       // float4 chunk id
            float4 f = ((const float4*)enc)[idx4];
            ushort4 u;
            u.x = f2bf(f.x); u.y = f2bf(f.y); u.z = f2bf(f.z); u.w = f2bf(f.w);
            ((ushort4*)ebf)[idx4] = u;
            return;
        }
        b -= 32768;
    }
    if (b < 1024) {
        // W2 = attn_w[:, 2048:3072] -> bf16 row-major (N=1024 x K=1024)
        int idx4 = b * 256 + threadIdx.x;
        int n = idx4 >> 8;
        int c = (idx4 & 255) * 4;
        float4 f = *(const float4*)(attn_w + (size_t)n * H3 + H2 + c);
        ushort4 u;
        u.x = f2bf(f.x); u.y = f2bf(f.y); u.z = f2bf(f.z); u.w = f2bf(f.w);
        *(ushort4*)(w2b + (size_t)n * H + c) = u;
        return;
    }
    // dvec[i] = attn_b[i] + sum_{k<2048} hidden[k]*attn_w[i][k]
    b -= 1024;
    int wv = threadIdx.x >> 6, lane = threadIdx.x & 63;
    int row = b * 4 + wv;
    const float* wrow = attn_w + (size_t)row * H3;
    float s = 0.f;
    #pragma unroll
    for (int j = 0; j < 32; ++j) {
        int k = lane + j * 64;
        s += wrow[k] * hidden[k];
    }
    #pragma unroll
    for (int m = 1; m <= 32; m <<= 1) s += __shfl_xor(s, m);
    if (lane == 0) dvec[row] = s + attn_b[row];
}

// ---------- shared epilogue: tanh + v_w-dot + shuffle-reduce + atomic ----------
__device__ __forceinline__ void epilogue(const f32x4 acc[4][4], const float* __restrict__ dvec,
                                         const float* __restrict__ vw, float* __restrict__ logits,
                                         int rowBlock, int colBlock, int waveM, int waveN,
                                         int quad, int l16) {
    float rowsum[4][4];
    #pragma unroll
    for (int mi = 0; mi < 4; ++mi)
        #pragma unroll
        for (int r = 0; r < 4; ++r) rowsum[mi][r] = 0.f;

    #pragma unroll
    for (int ni = 0; ni < 4; ++ni) {
        int colg = colBlock * 128 + waveN * 64 + ni * 16 + l16;
        float dv = dvec[colg];
        float vv = vw[colg];
        #pragma unroll
        for (int mi = 0; mi < 4; ++mi)
            #pragma unroll
            for (int r = 0; r < 4; ++r)
                rowsum[mi][r] += tanh_fast(acc[mi][ni][r] + dv) * vv;
    }

    #pragma unroll
    for (int mi = 0; mi < 4; ++mi)
        #pragma unroll
        for (int r = 0; r < 4; ++r) {
            float s = rowsum[mi][r];
            s += __shfl_xor(s, 1);
            s += __shfl_xor(s, 2);
            s += __shfl_xor(s, 4);
            s += __shfl_xor(s, 8);
            rowsum[mi][r] = s;
        }

    if (l16 == 0) {
        int rbase = rowBlock * 128 + waveM * 64 + quad * 4;
        #pragma unroll
        for (int mi = 0; mi < 4; ++mi)
            #pragma unroll
            for (int r = 0; r < 4; ++r)
                atomicAdd(&logits[rbase + mi * 16 + r], rowsum[mi][r]);
    }
}

// ---------- FAST gemm: BK=64, XOR-swizzled LDS, pure global_load_lds staging ----------
// tile BM=128 BN=128 BK=64; 256 threads (2x2 waves, 64x64/wave); 16 k-iterations
// LDS layout: row r (128 B) holds 8 16B chunks; slot j stores k-chunk (j ^ (r&7)).
// Swizzle applied on the GLOBAL source address so global_load_lds keeps the
// mandatory wave-uniform-base + lane*16 LDS addressing. Consumer ds_read_b128
// at slot (kk*4+quad)^(l16&7): per instruction each 4-bank group serves exactly
// 8 lanes -> even bank load (stride-128 unswizzled would be 16-way conflicted).
__global__ __launch_bounds__(256, 2) void attn_gemm_fast(
        const unsigned short* __restrict__ ebf, const unsigned short* __restrict__ w2b,
        const float* __restrict__ dvec, const float* __restrict__ vw,
        float* __restrict__ logits) {
    __shared__ unsigned short Atile[128 * 64];   // 16 KB
    __shared__ unsigned short Btile[128 * 64];   // 16 KB

    const int tid = threadIdx.x;
    const int colBlock = blockIdx.x & 7;         // fastest: 8 blocks share one A tile
    const int rowBlock = blockIdx.x >> 3;        // 0..255

    const int lane = tid & 63;
    const int wv = tid >> 6;
    const int waveM = wv >> 1, waveN = wv & 1;
    const int quad = lane >> 4, l16 = lane & 15;

    f32x4 acc[4][4];
    #pragma unroll
    for (int mi = 0; mi < 4; ++mi)
        #pragma unroll
        for (int ni = 0; ni < 4; ++ni)
            acc[mi][ni] = (f32x4){0.f, 0.f, 0.f, 0.f};

    const size_t aRow0 = (size_t)(rowBlock * 128) * H;
    const size_t bRow0 = (size_t)(colBlock * 128) * H;

    // staging: 4 chunks per thread per operand; c = chunk id 0..1023
    // row = c>>3, slot j = c&7, global k-chunk = j ^ (row&7)
    int srow[4], sk[4];
    #pragma unroll
    for (int p = 0; p < 4; ++p) {
        int c = p * 256 + tid;
        srow[p] = c >> 3;
        sk[p] = ((c & 7) ^ (srow[p] & 7)) * 8;   // element offset of swizzled chunk
    }

    for (int kt = 0; kt < 16; ++kt) {
        const int k0 = kt * 64;

        #pragma unroll
        for (int p = 0; p < 4; ++p) {
            int c = p * 256 + tid;
            async_copy16(ebf + aRow0 + (size_t)srow[p] * H + k0 + sk[p],
                         (char*)Atile + (size_t)c * 16);
        }
        #pragma unroll
        for (int p = 0; p < 4; ++p) {
            int c = p * 256 + tid;
            async_copy16(w2b + bRow0 + (size_t)srow[p] * H + k0 + sk[p],
                         (char*)Btile + (size_t)c * 16);
        }

        __syncthreads();   // drains vmcnt(0) before barrier (compiler-inserted)

        #pragma unroll
        for (int kk = 0; kk < 2; ++kk) {
            const int slot = ((kk * 4 + quad) ^ (l16 & 7)) * 16;   // byte offset in row
            bf16x8 af[4], bfr[4];
            #pragma unroll
            for (int i = 0; i < 4; ++i) {
                int ar = waveM * 64 + i * 16 + l16;
                int br = waveN * 64 + i * 16 + l16;
                af[i]  = *(const bf16x8*)((const char*)Atile + ar * 128 + slot);
                bfr[i] = *(const bf16x8*)((const char*)Btile + br * 128 + slot);
            }
            #pragma unroll
            for (int mi = 0; mi < 4; ++mi)
                #pragma unroll
                for (int ni = 0; ni < 4; ++ni)
                    acc[mi][ni] = __builtin_amdgcn_mfma_f32_16x16x32_bf16(
                        af[mi], bfr[ni], acc[mi][ni], 0, 0, 0);
        }

        __syncthreads();   // tile consumed; next iter may overwrite
    }

    epilogue(acc, dvec, vw, logits, rowBlock, colBlock, waveM, waveN, quad, l16);
}

// ---------- FALLBACK gemm (small ws): BK=32, inline fp32->bf16 A staging ----------
__global__ __launch_bounds__(256, 2) void attn_gemm_fb(
        const float* __restrict__ enc, const unsigned short* __restrict__ w2b,
        const float* __restrict__ dvec, const float* __restrict__ vw,
        float* __restrict__ logits) {
    __shared__ unsigned short Atile[128 * 32];
    __shared__ unsigned short Btile[128 * 32];

    const int tid = threadIdx.x;
    const int rowBlock = blockIdx.x & 255;
    const int colBlock = blockIdx.x >> 8;

    const int lane = tid & 63;
    const int wv = tid >> 6;
    const int waveM = wv >> 1, waveN = wv & 1;
    const int quad = lane >> 4, l16 = lane & 15;

    f32x4 acc[4][4];
    #pragma unroll
    for (int mi = 0; mi < 4; ++mi)
        #pragma unroll
        for (int ni = 0; ni < 4; ++ni)
            acc[mi][ni] = (f32x4){0.f, 0.f, 0.f, 0.f};

    const int arow = tid >> 3;
    const int akc  = (tid & 7) * 4;
    const size_t encRowBase = (size_t)(rowBlock * 128) * H;

    const unsigned short* Abase = Atile + (waveM * 64 + l16) * 32 + quad * 8;
    const unsigned short* Bbase = Btile + (waveN * 64 + l16) * 32 + quad * 8;

    for (int kt = 0; kt < 32; ++kt) {
        const int k0 = kt * 32;
        #pragma unroll
        for (int p = 0; p < 2; ++p) {
            int c = p * 256 + tid;
            int n = c >> 2, kk = (c & 3) * 8;
            async_copy16(w2b + (size_t)(colBlock * 128 + n) * H + k0 + kk,
                         (char*)Btile + (size_t)c * 16);
        }
        float4 av[4];
        #pragma unroll
        for (int p = 0; p < 4; ++p)
            av[p] = *(const float4*)(enc + encRowBase + (size_t)(arow + p * 32) * H + k0 + akc);
        #pragma unroll
        for (int p = 0; p < 4; ++p) {
            uint2 u;
            u.x = cvt_pk(av[p].x, av[p].y);
            u.y = cvt_pk(av[p].z, av[p].w);
            *(uint2*)(Atile + (arow + p * 32) * 32 + akc) = u;
        }

        __syncthreads();

        bf16x8 af[4], bfr[4];
        #pragma unroll
        for (int i = 0; i < 4; ++i) {
            af[i]  = *(const bf16x8*)(Abase + i * 16 * 32);
            bfr[i] = *(const bf16x8*)(Bbase + i * 16 * 32);
        }
        #pragma unroll
        for (int mi = 0; mi < 4; ++mi)
            #pragma unroll
            for (int ni = 0; ni < 4; ++ni)
                acc[mi][ni] = __builtin_amdgcn_mfma_f32_16x16x32_bf16(
                    af[mi], bfr[ni], acc[mi][ni], 0, 0, 0);

        __syncthreads();
    }

    epilogue(acc, dvec, vw, logits, rowBlock, colBlock, waveM, waveN, quad, l16);
}

// ---------- softmax over 32768 logits, single workgroup, in-place ----------
__global__ __launch_bounds__(1024) void softmax_k(float* __restrict__ x) {
    __shared__ float red[16];
    const int tid = threadIdx.x;
    const int lane = tid & 63, wv = tid >> 6;

    float v[32];
    float m = -1e30f;
    #pragma unroll
    for (int i = 0; i < 32; ++i) {
        v[i] = x[tid + (i << 10)];
        m = fmaxf(m, v[i]);
    }
    #pragma unroll
    for (int o = 1; o < 64; o <<= 1) m = fmaxf(m, __shfl_xor(m, o));
    if (lane == 0) red[wv] = m;
    __syncthreads();
    #pragma unroll
    for (int i = 0; i < 16; ++i) m = fmaxf(m, red[i]);
    __syncthreads();

    float s = 0.f;
    #pragma unroll
    for (int i = 0; i < 32; ++i) {
        v[i] = expf(v[i] - m);
        s += v[i];
    }
    #pragma unroll
    for (int o = 1; o < 64; o <<= 1) s += __shfl_xor(s, o);
    if (lane == 0) red[wv] = s;
    __syncthreads();
    float tot = 0.f;
    #pragma unroll
    for (int i = 0; i < 16; ++i) tot += red[i];
    float inv = 1.0f / tot;

    #pragma unroll
    for (int i = 0; i < 32; ++i) x[tid + (i << 10)] = v[i] * inv;
}

extern "C" void kernel_launch(void* const* d_in, const int* in_sizes, int n_in,
                              void* d_out, int out_size, void* d_ws, size_t ws_size,
                              hipStream_t stream) {
    const float* hidden = (const float*)d_in[0];   // (1, 2048)
    const float* enc    = (const float*)d_in[1];   // (32768, 1024)
    const float* attn_w = (const float*)d_in[2];   // (1024, 3072)
    const float* attn_b = (const float*)d_in[3];   // (1024,)
    const float* v_w    = (const float*)d_in[4];   // (1, 1024)
    float* out = (float*)d_out;                    // (32768,) fp32

    const size_t EBF_BYTES = (size_t)S * H * 2;    // 64 MB
    const size_t W2_BYTES  = (size_t)H * H * 2;    // 2 MB
    const bool fast = ws_size >= EBF_BYTES + W2_BYTES + 4096;

    if (fast) {
        unsigned short* ebf = (unsigned short*)d_ws;
        unsigned short* w2b = (unsigned short*)((char*)d_ws + EBF_BYTES);
        float* dvec = (float*)((char*)d_ws + EBF_BYTES + W2_BYTES);
        prep_all<<<dim3(32 + 32768 + 1024 + 256), dim3(256), 0, stream>>>(
            enc, attn_w, attn_b, hidden, ebf, w2b, dvec, out, 1);
        attn_gemm_fast<<<dim3(2048), dim3(256), 0, stream>>>(ebf, w2b, dvec, v_w, out);
    } else {
        unsigned short* w2b = (unsigned short*)d_ws;
        float* dvec = (float*)((char*)d_ws + W2_BYTES);
        prep_all<<<dim3(32 + 1024 + 256), dim3(256), 0, stream>>>(
            enc, attn_w, attn_b, hidden, nullptr, w2b, dvec, out, 0);
        attn_gemm_fb<<<dim3(2048), dim3(256), 0, stream>>>(enc, w2b, dvec, v_w, out);
    }
    softmax_k<<<dim3(1), dim3(1024), 0, stream>>>(out);
}

// Round 7
// 296.914 us; speedup vs baseline: 1.1124x; 1.0352x over previous
//
#include <hip/hip_runtime.h>
#include <hip/hip_bf16.h>

#define H  1024
#define S  32768
#define H2 2048
#define H3 3072

typedef __attribute__((ext_vector_type(8))) short bf16x8;   // 8 bf16 = 4 VGPRs
typedef __attribute__((ext_vector_type(4))) float f32x4;    // MFMA C/D frag

// ---------- fp32 -> bf16 (RNE) helpers ----------
__device__ __forceinline__ unsigned short f2bf(float f) {
    unsigned u = __float_as_uint(f);
    u += 0x7fffu + ((u >> 16) & 1u);
    return (unsigned short)(u >> 16);
}

__device__ __forceinline__ unsigned cvt_pk(float lo, float hi) {
    __hip_bfloat162 h = __float22bfloat162_rn(make_float2(lo, hi));
    unsigned u;
    __builtin_memcpy(&u, &h, 4);
    return u;
}

// fast tanh via v_exp_f32: tanh(x) = 1 - 2/(e^(2x)+1)
__device__ __forceinline__ float tanh_fast(float x) {
    float e = __expf(2.0f * x);
    return 1.0f - 2.0f / (e + 1.0f);
}

// ---------- async global->LDS 16B ----------
__device__ __forceinline__ void async_copy16(const void* g, void* l) {
    __builtin_amdgcn_global_load_lds(
        (const __attribute__((address_space(1))) unsigned int*)g,
        (__attribute__((address_space(3))) unsigned int*)l,
        16, 0, 0);
}

// ---------- fused prep: zero logits, enc->bf16 (fast path), W2->bf16, dvec ----------
// grid = 32 [+32768 if do_enc] + 1024 + 256
__global__ void prep_all(const float* __restrict__ enc, const float* __restrict__ attn_w,
                         const float* __restrict__ attn_b, const float* __restrict__ hidden,
                         unsigned short* __restrict__ ebf, unsigned short* __restrict__ w2b,
                         float* __restrict__ dvec, float* __restrict__ logits, int do_enc) {
    int b = blockIdx.x;
    if (b < 32) {
        // zero the logits (gemm accumulates via atomicAdd)
        ((float4*)logits)[b * 256 + threadIdx.x] = (float4){0.f, 0.f, 0.f, 0.f};
        return;
    }
    b -= 32;
    if (do_enc) {
        if (b < 32768) {
            size_t idx4 = (size_t)b * 256 + threadIdx.x;       // float4 chunk id
            float4 f = ((const float4*)enc)[idx4];
            ushort4 u;
            u.x = f2bf(f.x); u.y = f2bf(f.y); u.z = f2bf(f.z); u.w = f2bf(f.w);
            ((ushort4*)ebf)[idx4] = u;
            return;
        }
        b -= 32768;
    }
    if (b < 1024) {
        // W2 = attn_w[:, 2048:3072] -> bf16 row-major (N=1024 x K=1024)
        int idx4 = b * 256 + threadIdx.x;
        int n = idx4 >> 8;
        int c = (idx4 & 255) * 4;
        float4 f = *(const float4*)(attn_w + (size_t)n * H3 + H2 + c);
        ushort4 u;
        u.x = f2bf(f.x); u.y = f2bf(f.y); u.z = f2bf(f.z); u.w = f2bf(f.w);
        *(ushort4*)(w2b + (size_t)n * H + c) = u;
        return;
    }
    // dvec[i] = attn_b[i] + sum_{k<2048} hidden[k]*attn_w[i][k]
    b -= 1024;
    int wv = threadIdx.x >> 6, lane = threadIdx.x & 63;
    int row = b * 4 + wv;
    const float* wrow = attn_w + (size_t)row * H3;
    float s = 0.f;
    #pragma unroll
    for (int j = 0; j < 32; ++j) {
        int k = lane + j * 64;
        s += wrow[k] * hidden[k];
    }
    #pragma unroll
    for (int m = 1; m <= 32; m <<= 1) s += __shfl_xor(s, m);
    if (lane == 0) dvec[row] = s + attn_b[row];
}

// ---------- shared epilogue: tanh + v_w-dot + shuffle-reduce + atomic ----------
__device__ __forceinline__ void epilogue(const f32x4 acc[4][4], const float* __restrict__ dvec,
                                         const float* __restrict__ vw, float* __restrict__ logits,
                                         int rowBlock, int colBlock, int waveM, int waveN,
                                         int quad, int l16) {
    float rowsum[4][4];
    #pragma unroll
    for (int mi = 0; mi < 4; ++mi)
        #pragma unroll
        for (int r = 0; r < 4; ++r) rowsum[mi][r] = 0.f;

    #pragma unroll
    for (int ni = 0; ni < 4; ++ni) {
        int colg = colBlock * 128 + waveN * 64 + ni * 16 + l16;
        float dv = dvec[colg];
        float vv = vw[colg];
        #pragma unroll
        for (int mi = 0; mi < 4; ++mi)
            #pragma unroll
            for (int r = 0; r < 4; ++r)
                rowsum[mi][r] += tanh_fast(acc[mi][ni][r] + dv) * vv;
    }

    #pragma unroll
    for (int mi = 0; mi < 4; ++mi)
        #pragma unroll
        for (int r = 0; r < 4; ++r) {
            float s = rowsum[mi][r];
            s += __shfl_xor(s, 1);
            s += __shfl_xor(s, 2);
            s += __shfl_xor(s, 4);
            s += __shfl_xor(s, 8);
            rowsum[mi][r] = s;
        }

    if (l16 == 0) {
        int rbase = rowBlock * 128 + waveM * 64 + quad * 4;
        #pragma unroll
        for (int mi = 0; mi < 4; ++mi)
            #pragma unroll
            for (int r = 0; r < 4; ++r)
                atomicAdd(&logits[rbase + mi * 16 + r], rowsum[mi][r]);
    }
}

// ---------- FAST gemm: BK=64, XOR-swizzled LDS, pure global_load_lds staging ----------
// tile BM=128 BN=128 BK=64; 256 threads (2x2 waves, 64x64/wave); 16 k-iterations
// Grid decode: rowBlock = blockIdx&255 (fastest). Blocks dispatch round-robin
// over 8 XCDs (XCD ~ blockIdx%8); since 256 ≡ 0 (mod 8), all 8 colBlocks of a
// given rowBlock land on the SAME XCD -> one L2 fetch per A-tile. (Round-4
// evidence: colBlock-fastest decode put the 8 sharers on 8 different XCDs:
// FETCH_SIZE 78->264 MB. XCD affinity is the lever.)
// LDS layout: row r (128 B) holds 8 16B chunks; slot j stores k-chunk (j^(r&7)).
// Swizzle on the GLOBAL source address keeps global_load_lds's mandatory
// wave-uniform-base + lane*16 LDS addressing; consumer reads slot
// (kk*4+quad)^(l16&7) -> bank conflicts measured 0 (round 4).
// launch_bounds kept at (256,2) — the exact config that ran in round 4.
__global__ __launch_bounds__(256, 2) void attn_gemm_fast(
        const unsigned short* __restrict__ ebf, const unsigned short* __restrict__ w2b,
        const float* __restrict__ dvec, const float* __restrict__ vw,
        float* __restrict__ logits) {
    __shared__ unsigned short Atile[128 * 64];   // 16 KB
    __shared__ unsigned short Btile[128 * 64];   // 16 KB

    const int tid = threadIdx.x;
    const int rowBlock = blockIdx.x & 255;       // XCD-affine: row -> fixed XCD
    const int colBlock = blockIdx.x >> 8;        // 0..7

    const int lane = tid & 63;
    const int wv = tid >> 6;
    const int waveM = wv >> 1, waveN = wv & 1;
    const int quad = lane >> 4, l16 = lane & 15;

    f32x4 acc[4][4];
    #pragma unroll
    for (int mi = 0; mi < 4; ++mi)
        #pragma unroll
        for (int ni = 0; ni < 4; ++ni)
            acc[mi][ni] = (f32x4){0.f, 0.f, 0.f, 0.f};

    const size_t aRow0 = (size_t)(rowBlock * 128) * H;
    const size_t bRow0 = (size_t)(colBlock * 128) * H;

    // staging: 4 chunks per thread per operand; c = chunk id 0..1023
    // row = c>>3, slot j = c&7, global k-chunk = j ^ (row&7)
    int srow[4], sk[4];
    #pragma unroll
    for (int p = 0; p < 4; ++p) {
        int c = p * 256 + tid;
        srow[p] = c >> 3;
        sk[p] = ((c & 7) ^ (srow[p] & 7)) * 8;   // element offset of swizzled chunk
    }

    for (int kt = 0; kt < 16; ++kt) {
        const int k0 = kt * 64;

        #pragma unroll
        for (int p = 0; p < 4; ++p) {
            int c = p * 256 + tid;
            async_copy16(ebf + aRow0 + (size_t)srow[p] * H + k0 + sk[p],
                         (char*)Atile + (size_t)c * 16);
        }
        #pragma unroll
        for (int p = 0; p < 4; ++p) {
            int c = p * 256 + tid;
            async_copy16(w2b + bRow0 + (size_t)srow[p] * H + k0 + sk[p],
                         (char*)Btile + (size_t)c * 16);
        }

        __syncthreads();   // drains vmcnt(0) before barrier (compiler-inserted)

        #pragma unroll
        for (int kk = 0; kk < 2; ++kk) {
            const int slot = ((kk * 4 + quad) ^ (l16 & 7)) * 16;   // byte offset in row
            bf16x8 af[4], bfr[4];
            #pragma unroll
            for (int i = 0; i < 4; ++i) {
                int ar = waveM * 64 + i * 16 + l16;
                int br = waveN * 64 + i * 16 + l16;
                af[i]  = *(const bf16x8*)((const char*)Atile + ar * 128 + slot);
                bfr[i] = *(const bf16x8*)((const char*)Btile + br * 128 + slot);
            }
            #pragma unroll
            for (int mi = 0; mi < 4; ++mi)
                #pragma unroll
                for (int ni = 0; ni < 4; ++ni)
                    acc[mi][ni] = __builtin_amdgcn_mfma_f32_16x16x32_bf16(
                        af[mi], bfr[ni], acc[mi][ni], 0, 0, 0);
        }

        __syncthreads();   // tile consumed; next iter may overwrite
    }

    epilogue(acc, dvec, vw, logits, rowBlock, colBlock, waveM, waveN, quad, l16);
}

// ---------- FALLBACK gemm (small ws): BK=32, inline fp32->bf16 A staging ----------
__global__ __launch_bounds__(256, 2) void attn_gemm_fb(
        const float* __restrict__ enc, const unsigned short* __restrict__ w2b,
        const float* __restrict__ dvec, const float* __restrict__ vw,
        float* __restrict__ logits) {
    __shared__ unsigned short Atile[128 * 32];
    __shared__ unsigned short Btile[128 * 32];

    const int tid = threadIdx.x;
    const int rowBlock = blockIdx.x & 255;
    const int colBlock = blockIdx.x >> 8;

    const int lane = tid & 63;
    const int wv = tid >> 6;
    const int waveM = wv >> 1, waveN = wv & 1;
    const int quad = lane >> 4, l16 = lane & 15;

    f32x4 acc[4][4];
    #pragma unroll
    for (int mi = 0; mi < 4; ++mi)
        #pragma unroll
        for (int ni = 0; ni < 4; ++ni)
            acc[mi][ni] = (f32x4){0.f, 0.f, 0.f, 0.f};

    const int arow = tid >> 3;
    const int akc  = (tid & 7) * 4;
    const size_t encRowBase = (size_t)(rowBlock * 128) * H;

    const unsigned short* Abase = Atile + (waveM * 64 + l16) * 32 + quad * 8;
    const unsigned short* Bbase = Btile + (waveN * 64 + l16) * 32 + quad * 8;

    for (int kt = 0; kt < 32; ++kt) {
        const int k0 = kt * 32;
        #pragma unroll
        for (int p = 0; p < 2; ++p) {
            int c = p * 256 + tid;
            int n = c >> 2, kk = (c & 3) * 8;
            async_copy16(w2b + (size_t)(colBlock * 128 + n) * H + k0 + kk,
                         (char*)Btile + (size_t)c * 16);
        }
        float4 av[4];
        #pragma unroll
        for (int p = 0; p < 4; ++p)
            av[p] = *(const float4*)(enc + encRowBase + (size_t)(arow + p * 32) * H + k0 + akc);
        #pragma unroll
        for (int p = 0; p < 4; ++p) {
            uint2 u;
            u.x = cvt_pk(av[p].x, av[p].y);
            u.y = cvt_pk(av[p].z, av[p].w);
            *(uint2*)(Atile + (arow + p * 32) * 32 + akc) = u;
        }

        __syncthreads();

        bf16x8 af[4], bfr[4];
        #pragma unroll
        for (int i = 0; i < 4; ++i) {
            af[i]  = *(const bf16x8*)(Abase + i * 16 * 32);
            bfr[i] = *(const bf16x8*)(Bbase + i * 16 * 32);
        }
        #pragma unroll
        for (int mi = 0; mi < 4; ++mi)
            #pragma unroll
            for (int ni = 0; ni < 4; ++ni)
                acc[mi][ni] = __builtin_amdgcn_mfma_f32_16x16x32_bf16(
                    af[mi], bfr[ni], acc[mi][ni], 0, 0, 0);

        __syncthreads();
    }

    epilogue(acc, dvec, vw, logits, rowBlock, colBlock, waveM, waveN, quad, l16);
}

// ---------- softmax over 32768 logits, single workgroup, in-place ----------
__global__ __launch_bounds__(1024) void softmax_k(float* __restrict__ x) {
    __shared__ float red[16];
    const int tid = threadIdx.x;
    const int lane = tid & 63, wv = tid >> 6;

    float v[32];
    float m = -1e30f;
    #pragma unroll
    for (int i = 0; i < 32; ++i) {
        v[i] = x[tid + (i << 10)];
        m = fmaxf(m, v[i]);
    }
    #pragma unroll
    for (int o = 1; o < 64; o <<= 1) m = fmaxf(m, __shfl_xor(m, o));
    if (lane == 0) red[wv] = m;
    __syncthreads();
    #pragma unroll
    for (int i = 0; i < 16; ++i) m = fmaxf(m, red[i]);
    __syncthreads();

    float s = 0.f;
    #pragma unroll
    for (int i = 0; i < 32; ++i) {
        v[i] = expf(v[i] - m);
        s += v[i];
    }
    #pragma unroll
    for (int o = 1; o < 64; o <<= 1) s += __shfl_xor(s, o);
    if (lane == 0) red[wv] = s;
    __syncthreads();
    float tot = 0.f;
    #pragma unroll
    for (int i = 0; i < 16; ++i) tot += red[i];
    float inv = 1.0f / tot;

    #pragma unroll
    for (int i = 0; i < 32; ++i) x[tid + (i << 10)] = v[i] * inv;
}

extern "C" void kernel_launch(void* const* d_in, const int* in_sizes, int n_in,
                              void* d_out, int out_size, void* d_ws, size_t ws_size,
                              hipStream_t stream) {
    const float* hidden = (const float*)d_in[0];   // (1, 2048)
    const float* enc    = (const float*)d_in[1];   // (32768, 1024)
    const float* attn_w = (const float*)d_in[2];   // (1024, 3072)
    const float* attn_b = (const float*)d_in[3];   // (1024,)
    const float* v_w    = (const float*)d_in[4];   // (1, 1024)
    float* out = (float*)d_out;                    // (32768,) fp32

    const size_t EBF_BYTES = (size_t)S * H * 2;    // 64 MB
    const size_t W2_BYTES  = (size_t)H * H * 2;    // 2 MB
    const bool fast = ws_size >= EBF_BYTES + W2_BYTES + 4096;

    if (fast) {
        unsigned short* ebf = (unsigned short*)d_ws;
        unsigned short* w2b = (unsigned short*)((char*)d_ws + EBF_BYTES);
        float* dvec = (float*)((char*)d_ws + EBF_BYTES + W2_BYTES);
        prep_all<<<dim3(32 + 32768 + 1024 + 256), dim3(256), 0, stream>>>(
            enc, attn_w, attn_b, hidden, ebf, w2b, dvec, out, 1);
        attn_gemm_fast<<<dim3(2048), dim3(256), 0, stream>>>(ebf, w2b, dvec, v_w, out);
    } else {
        unsigned short* w2b = (unsigned short*)d_ws;
        float* dvec = (float*)((char*)d_ws + W2_BYTES);
        prep_all<<<dim3(32 + 1024 + 256), dim3(256), 0, stream>>>(
            enc, attn_w, attn_b, hidden, nullptr, w2b, dvec, out, 0);
        attn_gemm_fb<<<dim3(2048), dim3(256), 0, stream>>>(enc, w2b, dvec, v_w, out);
    }
    softmax_k<<<dim3(1), dim3(1024), 0, stream>>>(out);
}